// Round 1
// baseline (4642.266 us; speedup 1.0000x reference)
//
#include <hip/hip_runtime.h>
#include <hip/hip_bf16.h>

#define BATCH 64
#define SEQ   512
#define ISZ   1024
#define HID   1024
#define OUTSEQ_ELEMS (BATCH * SEQ * HID)   // 33554432
#define NBLK_RNN 64

typedef float f32x4 __attribute__((ext_vector_type(4)));
typedef short bf16x8 __attribute__((ext_vector_type(8)));

__device__ __forceinline__ unsigned short f2bf(float f) {
    union { float f; unsigned u; } v; v.f = f;
    unsigned r = v.u + 0x7fffu + ((v.u >> 16) & 1u);   // RNE
    return (unsigned short)(r >> 16);
}

// ---------------------------------------------------------------------------
// Kernel A: xp[m][n] = input[m][:] . Wx[:][n] + b[n], written into d_out
// (out_seq region, same [b*512+t][n] flattening). bf16 MFMA 16x16x32,
// 128x128 tile, BK=64, reg-staged fp32->bf16 conversion into padded LDS.
// ---------------------------------------------------------------------------
__global__ __launch_bounds__(256)
void xproj_gemm(const float* __restrict__ A, const float* __restrict__ W,
                const float* __restrict__ bias, float* __restrict__ C)
{
    __shared__ __align__(16) unsigned short As[128][72];  // [m][k], +8 pad
    __shared__ __align__(16) unsigned short Bs[128][72];  // [n][k] transposed, +8 pad
    const int tid  = threadIdx.x;
    const int lane = tid & 63;
    const int wave = tid >> 6;
    const int m0 = blockIdx.y * 128;
    const int n0 = blockIdx.x * 128;
    const int wm = (wave >> 1) * 64;
    const int wn = (wave & 1) * 64;
    const int l15 = lane & 15;
    const int kq8 = (lane >> 4) * 8;

    f32x4 acc[4][4] = {};

    for (int k0 = 0; k0 < ISZ; k0 += 64) {
        // stage A-tile 128x64
        #pragma unroll
        for (int i = 0; i < 8; ++i) {
            int idx = tid + i * 256;
            int row = idx >> 4;
            int kq  = idx & 15;
            float4 v = *reinterpret_cast<const float4*>(
                A + (size_t)(m0 + row) * ISZ + k0 + kq * 4);
            unsigned short* dst = &As[row][kq * 4];
            dst[0] = f2bf(v.x); dst[1] = f2bf(v.y);
            dst[2] = f2bf(v.z); dst[3] = f2bf(v.w);
        }
        // stage B-tile 64x128 transposed -> Bs[n][k]
        #pragma unroll
        for (int i = 0; i < 8; ++i) {
            int idx = tid + i * 256;
            int kk = idx >> 5;
            int nq = idx & 31;
            float4 v = *reinterpret_cast<const float4*>(
                W + (size_t)(k0 + kk) * HID + n0 + nq * 4);
            Bs[nq * 4 + 0][kk] = f2bf(v.x);
            Bs[nq * 4 + 1][kk] = f2bf(v.y);
            Bs[nq * 4 + 2][kk] = f2bf(v.z);
            Bs[nq * 4 + 3][kk] = f2bf(v.w);
        }
        __syncthreads();
        #pragma unroll
        for (int kk = 0; kk < 64; kk += 32) {
            const int krd = kk + kq8;
            bf16x8 a[4], b[4];
            #pragma unroll
            for (int mf = 0; mf < 4; ++mf)
                a[mf] = *reinterpret_cast<const bf16x8*>(&As[wm + mf * 16 + l15][krd]);
            #pragma unroll
            for (int nf = 0; nf < 4; ++nf)
                b[nf] = *reinterpret_cast<const bf16x8*>(&Bs[wn + nf * 16 + l15][krd]);
            #pragma unroll
            for (int mf = 0; mf < 4; ++mf)
                #pragma unroll
                for (int nf = 0; nf < 4; ++nf)
                    acc[mf][nf] = __builtin_amdgcn_mfma_f32_16x16x32_bf16(
                        a[mf], b[nf], acc[mf][nf], 0, 0, 0);
        }
        __syncthreads();
    }

    const int r4 = (lane >> 4) * 4;
    #pragma unroll
    for (int nf = 0; nf < 4; ++nf) {
        int col = n0 + wn + nf * 16 + l15;
        float bv = bias[col];
        #pragma unroll
        for (int mf = 0; mf < 4; ++mf) {
            int row = m0 + wm + mf * 16 + r4;
            #pragma unroll
            for (int r = 0; r < 4; ++r)
                C[(size_t)(row + r) * HID + col] = acc[mf][nf][r] + bv;
        }
    }
}

// ---------------------------------------------------------------------------
// Kernel B: 512 sequential steps h = tanh(xp_t + h @ Wh), cooperative.
// 64 WGs x 256 thr; WG owns 16 hidden columns (Wh^T slice resident in LDS,
// bf16, staged once). h double-buffered bf16 [b][k] in ws. xp read from
// d_out and overwritten in place with h_t. Custom monotonic global barrier.
// ---------------------------------------------------------------------------
__global__ __launch_bounds__(256)
void rnn_steps(const float* __restrict__ W, const float* __restrict__ h0,
               float* __restrict__ out,
               unsigned short* __restrict__ hA, unsigned short* __restrict__ hB,
               unsigned int* __restrict__ barcnt)
{
    __shared__ __align__(16) unsigned short WhT[16][1032];  // [n][k], +8 pad
    const int tid  = threadIdx.x;
    const int lane = tid & 63;
    const int wave = tid >> 6;
    const int jb = blockIdx.x * 16;

    // stage Wh^T slice (Wh = W rows [1024,2048)) -> bf16 LDS, once
    #pragma unroll 4
    for (int i = 0; i < 64; ++i) {
        int flat = tid + i * 256;
        int k = flat >> 4;
        int n = flat & 15;
        WhT[n][k] = f2bf(W[(size_t)(ISZ + k) * HID + jb + n]);
    }
    // init h buffer A from h_0 (each block fills a 1024-element slice)
    {
        int base = blockIdx.x * 1024 + tid * 4;
        float4 v = *reinterpret_cast<const float4*>(h0 + base);
        hA[base + 0] = f2bf(v.x); hA[base + 1] = f2bf(v.y);
        hA[base + 2] = f2bf(v.z); hA[base + 3] = f2bf(v.w);
    }

    int barn = 0;
    auto gbar = [&]() {
        __syncthreads();
        ++barn;
        if (tid == 0) {
            __hip_atomic_fetch_add(barcnt, 1u, __ATOMIC_RELEASE,
                                   __HIP_MEMORY_SCOPE_AGENT);
            const unsigned target = (unsigned)NBLK_RNN * (unsigned)barn;
            while (__hip_atomic_load(barcnt, __ATOMIC_RELAXED,
                                     __HIP_MEMORY_SCOPE_AGENT) < target)
                __builtin_amdgcn_s_sleep(1);
            __builtin_amdgcn_fence(__ATOMIC_ACQUIRE, "agent");
        }
        __syncthreads();
    };
    gbar();  // h init + WhT visible

    const int l15  = lane & 15;
    const int kq   = (lane >> 4) * 8;       // lane's k offset within 32-slice
    const int bm   = wave * 16;             // this wave's batch rows
    const int arow = bm + l15;              // A-operand row (batch)
    const int orow = bm + (lane >> 4) * 4;  // output rows base (+r)
    const int ocol = jb + l15;              // output column
    const unsigned short* bbase = &WhT[l15][kq];

    for (int t = 0; t < SEQ; ++t) {
        const unsigned short* cur = (t & 1) ? hB : hA;
        unsigned short*       nxt = (t & 1) ? hA : hB;

        // prefetch xp for this thread's 4 outputs
        float xp[4];
        #pragma unroll
        for (int r = 0; r < 4; ++r)
            xp[r] = out[(size_t)(orow + r) * (SEQ * HID) + (size_t)t * HID + ocol];

        const unsigned short* abase = cur + (size_t)arow * HID + kq;
        f32x4 ac0 = {}, ac1 = {}, ac2 = {}, ac3 = {};
        #pragma unroll
        for (int ks = 0; ks < 32; ks += 4) {   // 4 independent MFMA chains
            bf16x8 a0 = *reinterpret_cast<const bf16x8*>(abase + (ks + 0) * 32);
            bf16x8 a1 = *reinterpret_cast<const bf16x8*>(abase + (ks + 1) * 32);
            bf16x8 a2 = *reinterpret_cast<const bf16x8*>(abase + (ks + 2) * 32);
            bf16x8 a3 = *reinterpret_cast<const bf16x8*>(abase + (ks + 3) * 32);
            bf16x8 b0 = *reinterpret_cast<const bf16x8*>(bbase + (ks + 0) * 32);
            bf16x8 b1 = *reinterpret_cast<const bf16x8*>(bbase + (ks + 1) * 32);
            bf16x8 b2 = *reinterpret_cast<const bf16x8*>(bbase + (ks + 2) * 32);
            bf16x8 b3 = *reinterpret_cast<const bf16x8*>(bbase + (ks + 3) * 32);
            ac0 = __builtin_amdgcn_mfma_f32_16x16x32_bf16(a0, b0, ac0, 0, 0, 0);
            ac1 = __builtin_amdgcn_mfma_f32_16x16x32_bf16(a1, b1, ac1, 0, 0, 0);
            ac2 = __builtin_amdgcn_mfma_f32_16x16x32_bf16(a2, b2, ac2, 0, 0, 0);
            ac3 = __builtin_amdgcn_mfma_f32_16x16x32_bf16(a3, b3, ac3, 0, 0, 0);
        }
        f32x4 acc = (ac0 + ac1) + (ac2 + ac3);

        #pragma unroll
        for (int r = 0; r < 4; ++r) {
            float v = tanhf(acc[r] + xp[r]);
            size_t oidx = (size_t)(orow + r) * (SEQ * HID) + (size_t)t * HID + ocol;
            out[oidx] = v;                                        // h_t into out_seq
            nxt[(size_t)(orow + r) * HID + ocol] = f2bf(v);       // bf16 h for next step
            if (t == SEQ - 1)
                out[(size_t)OUTSEQ_ELEMS + (size_t)(orow + r) * HID + ocol] = v;  // h_n
        }
        gbar();
    }
}

extern "C" void kernel_launch(void* const* d_in, const int* in_sizes, int n_in,
                              void* d_out, int out_size, void* d_ws, size_t ws_size,
                              hipStream_t stream)
{
    const float* input = (const float*)d_in[0];
    const float* h0    = (const float*)d_in[1];
    const float* W     = (const float*)d_in[2];
    const float* bias  = (const float*)d_in[3];
    float* out = (float*)d_out;

    unsigned short* hA = (unsigned short*)d_ws;
    unsigned short* hB = hA + BATCH * HID;
    unsigned int* barcnt =
        (unsigned int*)((char*)d_ws + (size_t)2 * BATCH * HID * sizeof(unsigned short));

    dim3 gA(HID / 128, (BATCH * SEQ) / 128);   // (8, 256)
    xproj_gemm<<<gA, dim3(256), 0, stream>>>(input, W, bias, out);

    hipMemsetAsync(barcnt, 0, sizeof(unsigned int), stream);

    void* kargs[] = { (void*)&W, (void*)&h0, (void*)&out,
                      (void*)&hA, (void*)&hB, (void*)&barcnt };
    hipLaunchCooperativeKernel((const void*)rnn_steps, dim3(NBLK_RNN), dim3(256),
                               kargs, 0, stream);
}